// Round 3
// baseline (2842.365 us; speedup 1.0000x reference)
//
#include <hip/hip_runtime.h>

#define T_STEPS 512
#define BATCH   32
#define DIM     256
#define UNITS   256
#define COLS4U  1024

typedef _Float16 half8  __attribute__((ext_vector_type(8)));
typedef _Float16 half4v __attribute__((ext_vector_type(4)));
typedef float    f32x4  __attribute__((ext_vector_type(4)));
typedef unsigned long long ull;
typedef ull      ull2   __attribute__((ext_vector_type(2)));

__device__ __forceinline__ float fsig(float x){ return 1.0f/(1.0f+__expf(-x)); }
__device__ __forceinline__ float ftanh(float x){
  float xx = fminf(fmaxf(x,-15.f),15.f);
  float e = __expf(2.f*xx);
  return (e-1.f)/(e+1.f);
}

// byte offset into a [32][256] f16 LDS plane, XOR-swizzled 16B granules
__device__ __forceinline__ int swz(int b, int u){
  int g = u >> 3;
  int s = (g & 7) ^ (b & 7);
  return b*512 + (g>>3)*128 + s*16 + (u & 7)*2;
}

// ============================================================================
// Phase 1: xp[dir][t][col][b] (fp16) = bias[col] + sum_d x[b,tin,d] * Wk[d,col]
// grid = 2 dir x 8 colgroups(128) x 32 tgroups(16) = 512 blocks, 256 thr
// ============================================================================
__global__ __launch_bounds__(256, 2) void xproj(
    const float* __restrict__ x,
    const float* __restrict__ Wk_f, const float* __restrict__ b_f,
    const float* __restrict__ Wk_b, const float* __restrict__ b_b,
    _Float16* __restrict__ xph)
{
  const int bx  = blockIdx.x;
  const int dir = bx >> 8;
  const int cg  = (bx >> 5) & 7;
  const int tg  = bx & 31;
  const int tid = threadIdx.x;
  const int w   = tid >> 6;
  const int lane= tid & 63;
  const int l15 = lane & 15;
  const int l4  = lane >> 4;

  const float* Wk = dir ? Wk_b : Wk_f;
  const float* bs = dir ? b_b  : b_f;

  const int col0 = cg*128 + w*32;    // wave covers 32 cols = 2 ntiles

  // B fragments (weights), loaded once per block
  half8 Bf[2][8];
  float bias[2];
#pragma unroll
  for (int nt=0; nt<2; nt++){
    const int col = col0 + nt*16 + l15;
    bias[nt] = bs[col];
#pragma unroll
    for (int kk=0; kk<8; kk++){
      half8 v;
#pragma unroll
      for (int r=0; r<8; r++) v[r] = (_Float16)Wk[(size_t)(kk*32 + l4*8 + r)*COLS4U + col];
      Bf[nt][kk] = v;
    }
  }

  for (int tt=0; tt<16; ++tt){
    const int t   = tg*16 + tt;
    const int tin = dir ? (T_STEPS-1-t) : t;

    half8 Af[2][8];   // [mtile][kk]
#pragma unroll
    for (int mt=0; mt<2; mt++){
      const int b = mt*16 + l15;
#pragma unroll
      for (int kk=0; kk<8; kk++){
        const float* xp_ = x + ((size_t)b*T_STEPS + tin)*DIM + kk*32 + l4*8;
        f32x4 u0 = *(const f32x4*)xp_;
        f32x4 u1 = *(const f32x4*)(xp_ + 4);
        half8 v;
        v[0]=(_Float16)u0[0]; v[1]=(_Float16)u0[1]; v[2]=(_Float16)u0[2]; v[3]=(_Float16)u0[3];
        v[4]=(_Float16)u1[0]; v[5]=(_Float16)u1[1]; v[6]=(_Float16)u1[2]; v[7]=(_Float16)u1[3];
        Af[mt][kk] = v;
      }
    }

    f32x4 acc[2][2];  // [nt][mt]
#pragma unroll
    for (int nt=0; nt<2; nt++){
      f32x4 a; a[0]=bias[nt]; a[1]=bias[nt]; a[2]=bias[nt]; a[3]=bias[nt];
      acc[nt][0]=a; acc[nt][1]=a;
    }
#pragma unroll
    for (int kk=0; kk<8; kk++)
#pragma unroll
      for (int nt=0; nt<2; nt++)
#pragma unroll
        for (int mt=0; mt<2; mt++)
          acc[nt][mt] = __builtin_amdgcn_mfma_f32_16x16x32_f16(Af[mt][kk], Bf[nt][kk], acc[nt][mt], 0,0,0);

#pragma unroll
    for (int nt=0; nt<2; nt++){
      const int col = col0 + nt*16 + l15;
#pragma unroll
      for (int mt=0; mt<2; mt++){
        half4v o;
        o[0]=(_Float16)acc[nt][mt][0]; o[1]=(_Float16)acc[nt][mt][1];
        o[2]=(_Float16)acc[nt][mt][2]; o[3]=(_Float16)acc[nt][mt][3];
        *(ull*)(xph + ((size_t)(dir*T_STEPS + t)*COLS4U + col)*BATCH + mt*16 + l4*4)
            = __builtin_bit_cast(ull, o);
      }
    }
  }
}

// ============================================================================
// Phase 2: persistent scan. 4 blocks (2/dir x 2 halves of 128 units), 512 thr.
// h exchange via tagged u32 words: (fp16_bits<<16) | ((t+1)&0xFFFF).
// ============================================================================
__global__ __launch_bounds__(512, 2) void bilstm_scan4(
    const float* __restrict__ Wr_f, const float* __restrict__ Wr_b,
    float* __restrict__ out,
    const _Float16* __restrict__ xph,
    unsigned* __restrict__ slices)    // [2 par][2 dir][2 half][32][128] u32
{
  const int dir  = blockIdx.x >> 1;
  const int half = blockIdx.x & 1;
  const int tid  = threadIdx.x;
  const int w    = tid >> 6;          // 0..7
  const int lane = tid & 63;
  const int l15  = lane & 15;
  const int l4   = lane >> 4;

  const float* Wr = dir ? Wr_b : Wr_f;

  const int uloc   = w*16 + l15;          // 0..127 local unit
  const int unit   = half*128 + uloc;     // 0..255 unit within direction
  const int outcol = dir*256 + unit;

  __shared__ _Float16 hlds[2][BATCH*UNITS];   // ping-pong, swizzled

  // Wr fragments: Bf[gate][kk], col = gate*256 + unit
  half8 Bf[4][8];
#pragma unroll
  for (int q=0; q<4; q++){
    const int col = q*256 + unit;
#pragma unroll
    for (int kk=0; kk<8; kk++){
      half8 v;
#pragma unroll
      for (int r=0; r<8; r++) v[r] = (_Float16)Wr[(size_t)(kk*32 + l4*8 + r)*COLS4U + col];
      Bf[q][kk] = v;
      __builtin_amdgcn_sched_barrier(0);
    }
  }

  // zero h plane 0
  {
    half8 z;
#pragma unroll
    for (int e=0; e<8; e++) z[e] = (_Float16)0.f;
    for (int i=tid; i<BATCH*UNITS/8; i+=512) ((half8*)hlds[0])[i] = z;
  }
  __syncthreads();

  // reader role: lane reads peer words [b_r][c0..c0+7]
  const int b_r = tid >> 4;            // 0..31
  const int c0  = (tid & 15) * 8;      // 0..120
  const int pbase = (1-half)*128;

  float cst[8];
#pragma unroll
  for (int i=0;i<8;i++) cst[i]=0.f;
  bool spin_ok = true;

  // preload xp for t=0
  ull xpv[8];
#pragma unroll
  for (int q=0;q<4;q++)
#pragma unroll
    for (int mt=0;mt<2;mt++)
      xpv[q*2+mt] = *(const ull*)(xph + ((size_t)(dir*T_STEPS + 0)*COLS4U + q*256+unit)*BATCH + mt*16 + l4*4);

  for (int t=0; t<T_STEPS; ++t){
    // ---- acc init from xp (bias + x@Wk folded in) ----
    f32x4 acc[2][4];
#pragma unroll
    for (int q=0;q<4;q++)
#pragma unroll
      for (int mt=0;mt<2;mt++){
        half4v hv = __builtin_bit_cast(half4v, xpv[q*2+mt]);
        f32x4 a; a[0]=(float)hv[0]; a[1]=(float)hv[1]; a[2]=(float)hv[2]; a[3]=(float)hv[3];
        acc[mt][q] = a;
      }

    // ---- z += h_t @ Wr ----
    const char* hpl = (const char*)hlds[t&1];
#pragma unroll
    for (int kk=0; kk<8; kk++){
      const int ul = kk*32 + l4*8;
      half8 a0 = *(const half8*)(hpl + swz(l15,    ul));
      half8 a1 = *(const half8*)(hpl + swz(16+l15, ul));
#pragma unroll
      for (int q=0;q<4;q++){
        acc[0][q] = __builtin_amdgcn_mfma_f32_16x16x32_f16(a0, Bf[q][kk], acc[0][q], 0,0,0);
        acc[1][q] = __builtin_amdgcn_mfma_f32_16x16x32_f16(a1, Bf[q][kk], acc[1][q], 0,0,0);
      }
    }

    // ---- gates -> c,h ; own LDS write + tagged publish + out store ----
    const int tout = dir ? (T_STEPS-1-t) : t;
    const int par  = (t+1) & 1;
    unsigned* myslc = slices + ((size_t)(par*4 + dir*2 + half))*4096;
    const unsigned tgt_out = (unsigned)(t+1) & 0xFFFFu;
    char* hnx = (char*)hlds[(t+1)&1];
#pragma unroll
    for (int mt=0; mt<2; mt++){
#pragma unroll
      for (int r=0;r<4;r++){
        const int b = mt*16 + l4*4 + r;
        float iv = fsig (acc[mt][0][r]);
        float fv = fsig (acc[mt][1][r]);
        float gv = ftanh(acc[mt][2][r]);
        float ov = fsig (acc[mt][3][r]);
        float &c = cst[mt*4+r];
        c = fv*c + iv*gv;
        float hv = ov*ftanh(c);
        _Float16 hf = (_Float16)hv;
        if (t+1 < T_STEPS){
          unsigned word = ((unsigned)__builtin_bit_cast(unsigned short, hf) << 16) | tgt_out;
          __hip_atomic_store(&myslc[b*128 + uloc], word,
                             __ATOMIC_RELAXED, __HIP_MEMORY_SCOPE_AGENT);
        }
        *(_Float16*)(hnx + swz(b, unit)) = hf;
        out[((size_t)b*T_STEPS + tout)*(2*UNITS) + outcol] = hv;
        if (t == T_STEPS-1)
          out[(size_t)BATCH*T_STEPS*(2*UNITS) + (size_t)b*(2*UNITS) + outcol] = hv;
      }
    }

    // ---- prefetch xp(t+1), spin-read peer slice, stage into LDS ----
    if (t+1 < T_STEPS){
#pragma unroll
      for (int q=0;q<4;q++)
#pragma unroll
        for (int mt=0;mt<2;mt++)
          xpv[q*2+mt] = *(const ull*)(xph + ((size_t)(dir*T_STEPS + (t+1))*COLS4U + q*256+unit)*BATCH + mt*16 + l4*4);

      const ull* src = (const ull*)(slices + ((size_t)(par*4 + dir*2 + (1-half)))*4096
                                    + b_r*128 + c0);
      ull v0,v1,v2,v3;
      if (spin_ok){
        int sp = 0; bool ok;
        do {
          v0 = __hip_atomic_load(&src[0], __ATOMIC_RELAXED, __HIP_MEMORY_SCOPE_AGENT);
          v1 = __hip_atomic_load(&src[1], __ATOMIC_RELAXED, __HIP_MEMORY_SCOPE_AGENT);
          v2 = __hip_atomic_load(&src[2], __ATOMIC_RELAXED, __HIP_MEMORY_SCOPE_AGENT);
          v3 = __hip_atomic_load(&src[3], __ATOMIC_RELAXED, __HIP_MEMORY_SCOPE_AGENT);
          unsigned t0=(unsigned)v0, t1=(unsigned)(v0>>32), t2=(unsigned)v1, t3=(unsigned)(v1>>32);
          unsigned t4=(unsigned)v2, t5=(unsigned)(v2>>32), t6=(unsigned)v3, t7=(unsigned)(v3>>32);
          ok = ((t0&0xFFFF)==tgt_out) & ((t1&0xFFFF)==tgt_out) & ((t2&0xFFFF)==tgt_out)
             & ((t3&0xFFFF)==tgt_out) & ((t4&0xFFFF)==tgt_out) & ((t5&0xFFFF)==tgt_out)
             & ((t6&0xFFFF)==tgt_out) & ((t7&0xFFFF)==tgt_out);
          if (++sp > (1<<20)) { spin_ok = false; break; }
        } while(!ok);
      } else {
        v0 = __hip_atomic_load(&src[0], __ATOMIC_RELAXED, __HIP_MEMORY_SCOPE_AGENT);
        v1 = __hip_atomic_load(&src[1], __ATOMIC_RELAXED, __HIP_MEMORY_SCOPE_AGENT);
        v2 = __hip_atomic_load(&src[2], __ATOMIC_RELAXED, __HIP_MEMORY_SCOPE_AGENT);
        v3 = __hip_atomic_load(&src[3], __ATOMIC_RELAXED, __HIP_MEMORY_SCOPE_AGENT);
      }
      half8 hv;
      {
        unsigned wlo, whi;
        wlo=(unsigned)v0; whi=(unsigned)(v0>>32);
        hv[0]=__builtin_bit_cast(_Float16,(unsigned short)(wlo>>16));
        hv[1]=__builtin_bit_cast(_Float16,(unsigned short)(whi>>16));
        wlo=(unsigned)v1; whi=(unsigned)(v1>>32);
        hv[2]=__builtin_bit_cast(_Float16,(unsigned short)(wlo>>16));
        hv[3]=__builtin_bit_cast(_Float16,(unsigned short)(whi>>16));
        wlo=(unsigned)v2; whi=(unsigned)(v2>>32);
        hv[4]=__builtin_bit_cast(_Float16,(unsigned short)(wlo>>16));
        hv[5]=__builtin_bit_cast(_Float16,(unsigned short)(whi>>16));
        wlo=(unsigned)v3; whi=(unsigned)(v3>>32);
        hv[6]=__builtin_bit_cast(_Float16,(unsigned short)(wlo>>16));
        hv[7]=__builtin_bit_cast(_Float16,(unsigned short)(whi>>16));
      }
      *(half8*)(hnx + swz(b_r, pbase + c0)) = hv;
    }
    __syncthreads();
  }
}

// ============================================================================
// Fallback (round-2 kernel, proven): used when ws_size is too small for xp.
// ============================================================================
__global__ __launch_bounds__(256,1) void bilstm_mfma(
    const float* __restrict__ x,
    const float* __restrict__ Wk_f, const float* __restrict__ Wr_f, const float* __restrict__ b_f,
    const float* __restrict__ Wk_b, const float* __restrict__ Wr_b, const float* __restrict__ b_b,
    float* __restrict__ out,
    unsigned short* __restrict__ slices,
    unsigned* __restrict__ flags)
{
  const int dir = blockIdx.x >> 2;
  const int g4  = blockIdx.x & 3;
  const int tid = threadIdx.x;
  const int w   = tid >> 6;
  const int lane= tid & 63;
  const int l15 = lane & 15;
  const int l4  = lane >> 4;

  const float* Wk = dir ? Wk_b : Wk_f;
  const float* Wr = dir ? Wr_b : Wr_f;
  const float* bs = dir ? b_b  : b_f;

  const int u0b   = g4*64;
  const int upl   = u0b + w*16 + l15;
  const int outcol= dir*256 + upl;

  __shared__ _Float16 xlds[BATCH*DIM];
  __shared__ _Float16 hlds[2][BATCH*UNITS];

  half8 Bf[4][16];
#pragma unroll
  for (int q=0;q<4;q++){
    const int col = q*256 + upl;
#pragma unroll
    for (int kk=0;kk<16;kk++){
      const float* Ws = (kk<8) ? Wk : Wr;
      const int k0 = (kk&7)*32 + l4*8;
      half8 v;
#pragma unroll
      for (int r=0;r<8;r++) v[r] = (_Float16)Ws[(size_t)(k0+r)*COLS4U + col];
      Bf[q][kk] = v;
      __builtin_amdgcn_sched_barrier(0);
    }
  }

  float bias[4];
#pragma unroll
  for (int q=0;q<4;q++) bias[q] = bs[q*256 + upl];

  {
    half8 z;
#pragma unroll
    for (int e=0;e<8;e++) z[e] = (_Float16)0.f;
    for (int i=tid; i<BATCH*UNITS/8; i+=256) ((half8*)hlds[0])[i] = z;
  }

  const int bx  = tid >> 3;
  const int d0x = (tid & 7) * 32;
  float xr[32];
  {
    const int tin0 = dir ? (T_STEPS-1) : 0;
    const float* xp = x + ((size_t)bx*T_STEPS + tin0)*DIM + d0x;
#pragma unroll
    for (int i=0;i<8;i++){
      f32x4 v = *(const f32x4*)(xp + i*4);
      xr[i*4+0]=v[0]; xr[i*4+1]=v[1]; xr[i*4+2]=v[2]; xr[i*4+3]=v[3];
    }
#pragma unroll
    for (int j=0;j<4;j++){
      half8 hh;
#pragma unroll
      for (int e=0;e<8;e++) hh[e] = (_Float16)xr[j*8+e];
      *(half8*)((char*)xlds + swz(bx, d0x + j*8)) = hh;
    }
  }
  __syncthreads();

  float cst[8];
#pragma unroll
  for (int i=0;i<8;i++) cst[i]=0.f;
  bool spin_ok = true;

  for (int t=0; t<T_STEPS; ++t){
    if (t+1 < T_STEPS){
      const int tin = dir ? (T_STEPS-2-t) : (t+1);
      const float* xp = x + ((size_t)bx*T_STEPS + tin)*DIM + d0x;
#pragma unroll
      for (int i=0;i<8;i++){
        f32x4 v = *(const f32x4*)(xp + i*4);
        xr[i*4+0]=v[0]; xr[i*4+1]=v[1]; xr[i*4+2]=v[2]; xr[i*4+3]=v[3];
      }
    }

    f32x4 acc[2][4];
#pragma unroll
    for (int q=0;q<4;q++){
      f32x4 a; a[0]=bias[q]; a[1]=bias[q]; a[2]=bias[q]; a[3]=bias[q];
      acc[0][q]=a; acc[1][q]=a;
    }
    const char* hpl = (const char*)hlds[t&1];
#pragma unroll
    for (int kk=0;kk<16;kk++){
      const char* pl = (kk<8) ? (const char*)xlds : hpl;
      const int ul = (kk&7)*32 + l4*8;
      half8 a0 = *(const half8*)(pl + swz(l15,      ul));
      half8 a1 = *(const half8*)(pl + swz(16+l15,   ul));
#pragma unroll
      for (int q=0;q<4;q++){
        acc[0][q] = __builtin_amdgcn_mfma_f32_16x16x32_f16(a0, Bf[q][kk], acc[0][q], 0,0,0);
        acc[1][q] = __builtin_amdgcn_mfma_f32_16x16x32_f16(a1, Bf[q][kk], acc[1][q], 0,0,0);
      }
    }

    const int tout = dir ? (T_STEPS-1-t) : t;
    unsigned short* slc = slices + (((size_t)((t+1)&1))*8 + dir*4 + g4)*2048;
    char* hnx = (char*)hlds[(t+1)&1];
#pragma unroll
    for (int mt=0; mt<2; mt++){
#pragma unroll
      for (int r=0;r<4;r++){
        const int b = mt*16 + l4*4 + r;
        float iv = fsig (acc[mt][0][r]);
        float fv = fsig (acc[mt][1][r]);
        float gv = ftanh(acc[mt][2][r]);
        float ov = fsig (acc[mt][3][r]);
        float &c = cst[mt*4+r];
        c = fv*c + iv*gv;
        float hval = ov*ftanh(c);
        out[((size_t)b*T_STEPS + tout)*(2*UNITS) + outcol] = hval;
        if (t == T_STEPS-1)
          out[(size_t)BATCH*T_STEPS*(2*UNITS) + (size_t)b*(2*UNITS) + outcol] = hval;
        _Float16 hf = (_Float16)hval;
        *(_Float16*)(hnx + swz(b, upl)) = hf;
        if (t+1 < T_STEPS)
          __hip_atomic_store(&slc[b*64 + (w*16+l15)],
                             __builtin_bit_cast(unsigned short, hf),
                             __ATOMIC_RELAXED, __HIP_MEMORY_SCOPE_AGENT);
      }
    }
    __syncthreads();

    if (t+1 < T_STEPS){
      if (tid == 192)
        __hip_atomic_store(&flags[(dir*4+g4)*32], (unsigned)(t+1),
                           __ATOMIC_RELAXED, __HIP_MEMORY_SCOPE_AGENT);
#pragma unroll
      for (int j=0;j<4;j++){
        half8 hh;
#pragma unroll
        for (int e=0;e<8;e++) hh[e] = (_Float16)xr[j*8+e];
        *(half8*)((char*)xlds + swz(bx, d0x + j*8)) = hh;
      }
      if (w < 3){
        const int p = w + (w >= g4);
        const unsigned target = (unsigned)(t+1);
        if (spin_ok){
          int sp = 0;
          while (__hip_atomic_load(&flags[(dir*4+p)*32],
                                   __ATOMIC_RELAXED, __HIP_MEMORY_SCOPE_AGENT) < target){
            if (++sp > (1<<22)) { spin_ok = false; break; }
          }
        }
        const ull* src = (const ull*)(slices + (((size_t)((t+1)&1))*8 + dir*4 + p)*2048);
        const int bsl = lane >> 1;
        const int u00 = (lane & 1) * 32;
#pragma unroll
        for (int j=0;j<4;j++){
          ull v0 = __hip_atomic_load(&src[lane*8 + 2*j  ], __ATOMIC_RELAXED, __HIP_MEMORY_SCOPE_AGENT);
          ull v1 = __hip_atomic_load(&src[lane*8 + 2*j+1], __ATOMIC_RELAXED, __HIP_MEMORY_SCOPE_AGENT);
          ull2 vv; vv[0]=v0; vv[1]=v1;
          *(ull2*)(hnx + swz(bsl, p*64 + u00 + j*8)) = vv;
        }
      }
      __syncthreads();
    }
  }
}

extern "C" void kernel_launch(void* const* d_in, const int* in_sizes, int n_in,
                              void* d_out, int out_size, void* d_ws, size_t ws_size,
                              hipStream_t stream) {
  const float* x    = (const float*)d_in[0];
  const float* Wk_f = (const float*)d_in[1];
  const float* Wr_f = (const float*)d_in[2];
  const float* b_f  = (const float*)d_in[3];
  const float* Wk_b = (const float*)d_in[4];
  const float* Wr_b = (const float*)d_in[5];
  const float* b_b  = (const float*)d_in[6];
  float* out = (float*)d_out;

  const size_t XPH = (size_t)2*T_STEPS*COLS4U*BATCH*sizeof(_Float16);   // 64 MiB
  const size_t SL  = (size_t)2*2*2*BATCH*128*sizeof(unsigned);          // 128 KiB

  if (ws_size >= XPH + SL) {
    _Float16* xph    = (_Float16*)d_ws;
    unsigned* slices = (unsigned*)((char*)d_ws + XPH);
    xproj<<<512, 256, 0, stream>>>(x, Wk_f, b_f, Wk_b, b_b, xph);
    bilstm_scan4<<<4, 512, 0, stream>>>(Wr_f, Wr_b, out, xph, slices);
  } else {
    unsigned short* slices = (unsigned short*)d_ws;
    unsigned* flags = (unsigned*)((char*)d_ws + 65536);
    hipMemsetAsync((char*)d_ws + 65536, 0, 1024, stream);
    bilstm_mfma<<<8, 256, 0, stream>>>(x, Wk_f, Wr_f, b_f, Wk_b, Wr_b, b_b,
                                       out, slices, flags);
  }
}